// Round 6
// baseline (111.942 us; speedup 1.0000x reference)
//
#include <hip/hip_runtime.h>
#include <math.h>

#define NLIB 128
#define INFBITS 0x7F800000u

typedef float f32x4 __attribute__((ext_vector_type(4)));

static __device__ __forceinline__ int iclamp(int v, int lo, int hi) {
    return v < lo ? lo : (v > hi ? hi : v);
}

// ---------------------------------------------------------------------------
// Kernel 1: per-row squared distance ||z_lib[n]-z||^2 (128 blocks x 256 thr)
// + init of smin-bits buffers (one word per thread across the grid).
// ---------------------------------------------------------------------------
__global__ __launch_bounds__(256)
void row_dist_kernel(const float* __restrict__ z, const float* __restrict__ z_lib,
                     float* __restrict__ dist2, unsigned* __restrict__ sb0,
                     unsigned* __restrict__ sb1, unsigned* __restrict__ sb2) {
    const int n = blockIdx.x;
    const int tid = threadIdx.x, wave = tid >> 6, lane = tid & 63;
    // distributed init: 128*256 = 32768 >= 4116 words
    const int gid = n * 256 + tid;
    if (gid < 3136)      sb0[gid] = INFBITS;
    else if (gid < 3920) sb1[gid - 3136] = INFBITS;
    else if (gid < 4116) sb2[gid - 3920] = INFBITS;

    const f32x4 a = ((const f32x4*)(z_lib + (size_t)n * 1024))[tid];
    const f32x4 b = ((const f32x4*)z)[tid];
    f32x4 d = a - b;
    f32x4 s = d * d;
    float acc = s[0] + s[1] + s[2] + s[3];
    for (int off = 32; off > 0; off >>= 1) acc += __shfl_down(acc, off, 64);
    __shared__ float ws4[4];
    if (lane == 0) ws4[wave] = acc;
    __syncthreads();
    if (tid == 0) dist2[n] = ws4[0] + ws4[1] + ws4[2] + ws4[3];
}

// ---------------------------------------------------------------------------
// Kernel 2: rank-select k smallest -> idx[rank]=n, z_score.
// ---------------------------------------------------------------------------
__global__ __launch_bounds__(128)
void select_kernel(const float* __restrict__ dist2, const int* __restrict__ kp,
                   float* __restrict__ zscore, int* __restrict__ idx) {
    __shared__ float d[NLIB];
    __shared__ float contrib[NLIB];
    const int tid = threadIdx.x;
    d[tid] = dist2[tid];
    __syncthreads();
    const int k = *kp;
    const float dd = d[tid];
    int rank = 0;
#pragma unroll 8
    for (int m = 0; m < NLIB; ++m) {
        const float dm = d[m];
        rank += (dm < dd || (dm == dd && m < tid)) ? 1 : 0;
    }
    if (rank < k) idx[rank] = tid;
    contrib[tid] = (rank < k) ? sqrtf(dd) : 0.f;
    __syncthreads();
    if (tid == 0) {
        float s = 0.f;
        for (int m = 0; m < NLIB; ++m) s += contrib[m];   // fixed order
        zscore[0] = s / (float)k;
    }
}

// ---------------------------------------------------------------------------
// Kernel 3: FUSED dist+min, XCD-byte-balanced, 2 n-streams per block.
// 24 byte-uniform tiles (262KB lib each): QT = 64/32/16 quads for
// C = 256/512/1024. gridDim.x=24 -> tile t pins to XCD t%8 (fmap slice
// L2-resident, equal bytes/XCD). One fmap load feeds 2 lib streams
// (nontemporal: read-once, don't evict fmap). LDS-combine fixed order;
// atomicMin(uint bits) into smin. No intermediate buffer.
// ---------------------------------------------------------------------------
template <int C, int NQ, int QT>
static __device__ __forceinline__ void dist_min_level(const float* __restrict__ lib,
                                                      const float* __restrict__ fmap,
                                                      int img0, int img1, int qt,
                                                      unsigned* __restrict__ sb,
                                                      f32x4* __restrict__ partA,
                                                      f32x4* __restrict__ partB) {
    constexpr int G  = 256 / QT;       // channel groups per block
    constexpr int CW = C / G;          // channels per thread (= 64)
    const int tid = threadIdx.x;
    const int ql  = tid & (QT - 1);
    const int g   = tid / QT;
    const int q   = qt * QT + ql;
    const int qc  = q < NQ ? q : NQ - 1;     // clamp: dup same-address loads
    const f32x4* __restrict__ lp0 = (const f32x4*)lib + ((size_t)img0 * C + g * CW) * NQ + qc;
    const f32x4* __restrict__ lp1 = (const f32x4*)lib + ((size_t)img1 * C + g * CW) * NQ + qc;
    const f32x4* __restrict__ fp  = (const f32x4*)fmap + ((size_t)g * CW) * NQ + qc;
    f32x4 acc0 = {}, acc1 = {};
#pragma unroll 4
    for (int c = 0; c < CW; ++c) {
        f32x4 f  = fp[(size_t)c * NQ];
        f32x4 a0 = __builtin_nontemporal_load(lp0 + (size_t)c * NQ);
        f32x4 a1 = __builtin_nontemporal_load(lp1 + (size_t)c * NQ);
        f32x4 d0 = a0 - f;
        f32x4 d1 = a1 - f;
        acc0 += d0 * d0;
        acc1 += d1 * d1;
    }
    partA[tid] = acc0;
    partB[tid] = acc1;
    __syncthreads();
    if (tid < QT && q < NQ) {
        f32x4 s0 = partA[tid];
        f32x4 s1 = partB[tid];
#pragma unroll
        for (int gg = 1; gg < G; ++gg) {           // fixed order
            s0 += partA[gg * QT + tid];
            s1 += partB[gg * QT + tid];
        }
        atomicMin(sb + q * 4 + 0, __float_as_uint(s0[0]));
        atomicMin(sb + q * 4 + 1, __float_as_uint(s0[1]));
        atomicMin(sb + q * 4 + 2, __float_as_uint(s0[2]));
        atomicMin(sb + q * 4 + 3, __float_as_uint(s0[3]));
        atomicMin(sb + q * 4 + 0, __float_as_uint(s1[0]));
        atomicMin(sb + q * 4 + 1, __float_as_uint(s1[1]));
        atomicMin(sb + q * 4 + 2, __float_as_uint(s1[2]));
        atomicMin(sb + q * 4 + 3, __float_as_uint(s1[3]));
    }
}

__global__ __launch_bounds__(256)
void dist_min_kernel(const float* __restrict__ lib0, const float* __restrict__ fmap0,
                     const float* __restrict__ lib1, const float* __restrict__ fmap1,
                     const float* __restrict__ lib2, const float* __restrict__ fmap2,
                     const int* __restrict__ kp, const int* __restrict__ idx,
                     unsigned* __restrict__ sb0, unsigned* __restrict__ sb1,
                     unsigned* __restrict__ sb2) {
    __shared__ f32x4 partA[256];
    __shared__ f32x4 partB[256];
    const int k = *kp;
    const int n0 = blockIdx.y * 2;
    if (n0 >= k) return;
    const int n1 = (n0 + 1 < k) ? n0 + 1 : k - 1;   // dup stream if k odd
    const int t = blockIdx.x;                        // 0..23, pins to XCD t%8
    const int img0 = idx[n0], img1 = idx[n1];
    if (t < 13)      dist_min_level<256, 784, 64>(lib0, fmap0, img0, img1, t, sb0, partA, partB);
    else if (t < 20) dist_min_level<512, 196, 32>(lib1, fmap1, img0, img1, t - 13, sb1, partA, partB);
    else             dist_min_level<1024, 49, 16>(lib2, fmap2, img0, img1, t - 20, sb2, partA, partB);
}

// ---------------------------------------------------------------------------
// Kernel 4: FUSED upsample + sum + blur-H + blur-V. 14 band blocks x 16
// output rows. Stage 32 smap rows (reflected) in LDS, H-blur in LDS, V-blur
// reflection-free: hb[r] = Hblur(smap(reflect(y0-8+r))) makes the V tap at
// global row y+j-8 exactly LDS row (y+j-8)-(y0-8).
// ---------------------------------------------------------------------------
static __device__ __forceinline__ void samp(int o, float inv_f, int sz, int& i0, int& i1,
                                            float& fr) {
    float c  = (o + 0.5f) * inv_f - 0.5f;   // inv_f power of two: exact
    float fl = floorf(c);
    fr = c - fl;
    int i = (int)fl;
    i0 = iclamp(i, 0, sz - 1);
    i1 = iclamp(i + 1, 0, sz - 1);
}

static __device__ __forceinline__ float ldsq(const unsigned* __restrict__ sb, int w, int y, int x) {
    return sqrtf(__uint_as_float(sb[y * w + x]));
}

static __device__ __forceinline__ float bilerp_sq(const unsigned* __restrict__ sb, int w,
                                                  int y0, int y1, int x0, int x1,
                                                  float fy, float fx) {
    float a = ldsq(sb, w, y0, x0), b = ldsq(sb, w, y0, x1);
    float c = ldsq(sb, w, y1, x0), d = ldsq(sb, w, y1, x1);
    float top = a + (b - a) * fx;
    float bot = c + (d - c) * fx;
    return top + (bot - top) * fy;
}

static __device__ __forceinline__ int reflect224(int i) {
    if (i < 0) i = -i;
    if (i > 223) i = 446 - i;
    return i;
}

static __device__ __forceinline__ void gauss_w(float* w) {
    float tot = 0.f;
#pragma unroll
    for (int j = 0; j < 17; ++j) {
        float t = (j - 8) * 0.25f;
        w[j] = expf(-0.5f * t * t);
        tot += w[j];
    }
    float inv = 1.f / tot;
#pragma unroll
    for (int j = 0; j < 17; ++j) w[j] *= inv;
}

__global__ __launch_bounds__(256)
void up_blur_kernel(const unsigned* __restrict__ sb0, const unsigned* __restrict__ sb1,
                    const unsigned* __restrict__ sb2, float* __restrict__ outmap) {
    __shared__ float sm[32][224];   // smap at reflected rows y0-8+r
    __shared__ float hb[32][224];   // H-blurred
    const int y0 = blockIdx.x * 16;
    const int tid = threadIdx.x;
    float w[17];
    gauss_w(w);

    // phase 1: upsample+sum at (reflect(y0-8+r), x)
    for (int i = tid; i < 32 * 224; i += 256) {
        const int r = i / 224, x = i - r * 224;
        const int gy = reflect224(y0 - 8 + r);
        int yy0, yy1, xx0, xx1; float fy, fx;
        float v = 0.f;
        samp(gy, 0.25f, 56, yy0, yy1, fy);   samp(x, 0.25f, 56, xx0, xx1, fx);
        v += bilerp_sq(sb0, 56, yy0, yy1, xx0, xx1, fy, fx);
        samp(gy, 0.125f, 28, yy0, yy1, fy);  samp(x, 0.125f, 28, xx0, xx1, fx);
        v += bilerp_sq(sb1, 28, yy0, yy1, xx0, xx1, fy, fx);
        samp(gy, 0.0625f, 14, yy0, yy1, fy); samp(x, 0.0625f, 14, xx0, xx1, fx);
        v += bilerp_sq(sb2, 14, yy0, yy1, xx0, xx1, fy, fx);
        sm[r][x] = v;
    }
    __syncthreads();

    // phase 2: H-blur each staged row (col reflection inside the row)
    for (int i = tid; i < 32 * 224; i += 256) {
        const int r = i / 224, x = i - r * 224;
        float acc = 0.f;
#pragma unroll
        for (int j = 0; j < 17; ++j) acc += w[j] * sm[r][reflect224(x + j - 8)];
        hb[r][x] = acc;
    }
    __syncthreads();

    // phase 3: V-blur -> 16 output rows (LDS row index is reflection-free)
    for (int i = tid; i < 16 * 224; i += 256) {
        const int ry = i / 224, x = i - ry * 224;
        const int y = y0 + ry;
        float acc = 0.f;
#pragma unroll
        for (int j = 0; j < 17; ++j) acc += w[j] * hb[y + j - 8 - (y0 - 8)][x];
        outmap[y * 224 + x] = acc;
    }
}

// ---------------------------------------------------------------------------
// Launch
// ---------------------------------------------------------------------------
extern "C" void kernel_launch(void* const* d_in, const int* in_sizes, int n_in,
                              void* d_out, int out_size, void* d_ws, size_t ws_size,
                              hipStream_t stream) {
    const float* z     = (const float*)d_in[0];
    const float* z_lib = (const float*)d_in[1];
    const float* fmap0 = (const float*)d_in[2];
    const float* fmap1 = (const float*)d_in[3];
    const float* fmap2 = (const float*)d_in[4];
    const float* lib0  = (const float*)d_in[5];
    const float* lib1  = (const float*)d_in[6];
    const float* lib2  = (const float*)d_in[7];
    const int*   kp    = (const int*)d_in[8];
    float* out = (float*)d_out;

    // workspace layout (16B aligned)
    constexpr size_t OFF_IDX   = 0;        // 128 i32
    constexpr size_t OFF_DIST2 = 1024;     // 128 f32
    constexpr size_t OFF_SB0   = 2048;     // 3136 u32
    constexpr size_t OFF_SB1   = 16384;    // 784 u32
    constexpr size_t OFF_SB2   = 20480;    // 196 u32

    char* ws = (char*)d_ws;
    int*      idx   = (int*)(ws + OFF_IDX);
    float*    dist2 = (float*)(ws + OFF_DIST2);
    unsigned* sb0   = (unsigned*)(ws + OFF_SB0);
    unsigned* sb1   = (unsigned*)(ws + OFF_SB1);
    unsigned* sb2   = (unsigned*)(ws + OFF_SB2);

    // 1) row distances + smin init
    row_dist_kernel<<<dim3(NLIB), dim3(256), 0, stream>>>(z, z_lib, dist2, sb0, sb1, sb2);
    // 2) rank-select + z_score
    select_kernel<<<dim3(1), dim3(128), 0, stream>>>(dist2, kp, out, idx);
    // 3) fused per-level distances + min, 24 byte-uniform tiles, 2 n/block
    dist_min_kernel<<<dim3(24, 64), dim3(256), 0, stream>>>(
        lib0, fmap0, lib1, fmap1, lib2, fmap2, kp, idx, sb0, sb1, sb2);
    // 4) fused upsample + sum + blur-H + blur-V
    up_blur_kernel<<<dim3(14), dim3(256), 0, stream>>>(sb0, sb1, sb2, out + 1);
}

// Round 7
// 108.548 us; speedup vs baseline: 1.0313x; 1.0313x over previous
//
#include <hip/hip_runtime.h>
#include <math.h>

#define NLIB 128
#define INFBITS 0x7F800000u

typedef float f32x4 __attribute__((ext_vector_type(4)));

static __device__ __forceinline__ int iclamp(int v, int lo, int hi) {
    return v < lo ? lo : (v > hi ? hi : v);
}

// ---------------------------------------------------------------------------
// Kernel 1: per-row squared distance ||z_lib[n]-z||^2 (128 blocks x 256 thr)
// + init of smin-bits buffers (one word per thread across the grid).
// ---------------------------------------------------------------------------
__global__ __launch_bounds__(256)
void row_dist_kernel(const float* __restrict__ z, const float* __restrict__ z_lib,
                     float* __restrict__ dist2, unsigned* __restrict__ sb0,
                     unsigned* __restrict__ sb1, unsigned* __restrict__ sb2) {
    const int n = blockIdx.x;
    const int tid = threadIdx.x, wave = tid >> 6, lane = tid & 63;
    // distributed init: 128*256 = 32768 >= 4116 words
    const int gid = n * 256 + tid;
    if (gid < 3136)      sb0[gid] = INFBITS;
    else if (gid < 3920) sb1[gid - 3136] = INFBITS;
    else if (gid < 4116) sb2[gid - 3920] = INFBITS;

    const f32x4 a = ((const f32x4*)(z_lib + (size_t)n * 1024))[tid];
    const f32x4 b = ((const f32x4*)z)[tid];
    f32x4 d = a - b;
    f32x4 s = d * d;
    float acc = s[0] + s[1] + s[2] + s[3];
    for (int off = 32; off > 0; off >>= 1) acc += __shfl_down(acc, off, 64);
    __shared__ float ws4[4];
    if (lane == 0) ws4[wave] = acc;
    __syncthreads();
    if (tid == 0) dist2[n] = ws4[0] + ws4[1] + ws4[2] + ws4[3];
}

// ---------------------------------------------------------------------------
// Kernel 2: rank-select k smallest -> idx[rank]=n, z_score.
// ---------------------------------------------------------------------------
__global__ __launch_bounds__(128)
void select_kernel(const float* __restrict__ dist2, const int* __restrict__ kp,
                   float* __restrict__ zscore, int* __restrict__ idx) {
    __shared__ float d[NLIB];
    __shared__ float contrib[NLIB];
    const int tid = threadIdx.x;
    d[tid] = dist2[tid];
    __syncthreads();
    const int k = *kp;
    const float dd = d[tid];
    int rank = 0;
#pragma unroll 8
    for (int m = 0; m < NLIB; ++m) {
        const float dm = d[m];
        rank += (dm < dd || (dm == dd && m < tid)) ? 1 : 0;
    }
    if (rank < k) idx[rank] = tid;
    contrib[tid] = (rank < k) ? sqrtf(dd) : 0.f;
    __syncthreads();
    if (tid == 0) {
        float s = 0.f;
        for (int m = 0; m < NLIB; ++m) s += contrib[m];   // fixed order
        zscore[0] = s / (float)k;
    }
}

// ---------------------------------------------------------------------------
// Kernel 3: FUSED dist+min, XCD-byte-balanced (round-5 structure: 1 n/block,
// plain loads — NT loads + multi-stream regressed twice, do not reintroduce).
// 24 byte-uniform tiles (262KB lib each): QT = 64/32/16 quads for
// C = 256/512/1024. gridDim.x=24 -> tile t pins to XCD t%8 (fmap slice
// L2-resident, equal bytes/XCD). LDS-combine fixed order; atomicMin(uint
// bits) into smin. No intermediate buffer.
// ---------------------------------------------------------------------------
template <int C, int NQ, int QT>
static __device__ __forceinline__ void dist_min_level(const float* __restrict__ lib,
                                                      const float* __restrict__ fmap,
                                                      int img, int qt,
                                                      unsigned* __restrict__ sb,
                                                      f32x4* __restrict__ part) {
    constexpr int G  = 256 / QT;       // channel groups per block
    constexpr int CW = C / G;          // channels per thread (= 64)
    const int tid = threadIdx.x;
    const int ql  = tid & (QT - 1);
    const int g   = tid / QT;
    const int q   = qt * QT + ql;
    const int qc  = q < NQ ? q : NQ - 1;     // clamp: dup same-address loads
    const f32x4* __restrict__ lp = (const f32x4*)lib + ((size_t)img * C + g * CW) * NQ + qc;
    const f32x4* __restrict__ fp = (const f32x4*)fmap + ((size_t)g * CW) * NQ + qc;
    f32x4 acc = {};
#pragma unroll 8
    for (int c = 0; c < CW; ++c) {
        f32x4 a = lp[(size_t)c * NQ];
        f32x4 f = fp[(size_t)c * NQ];
        f32x4 d = a - f;
        acc += d * d;
    }
    part[tid] = acc;
    __syncthreads();
    if (tid < QT && q < NQ) {
        f32x4 s = part[tid];
#pragma unroll
        for (int gg = 1; gg < G; ++gg) s += part[gg * QT + tid];  // fixed order
        atomicMin(sb + q * 4 + 0, __float_as_uint(s[0]));
        atomicMin(sb + q * 4 + 1, __float_as_uint(s[1]));
        atomicMin(sb + q * 4 + 2, __float_as_uint(s[2]));
        atomicMin(sb + q * 4 + 3, __float_as_uint(s[3]));
    }
}

__global__ __launch_bounds__(256)
void dist_min_kernel(const float* __restrict__ lib0, const float* __restrict__ fmap0,
                     const float* __restrict__ lib1, const float* __restrict__ fmap1,
                     const float* __restrict__ lib2, const float* __restrict__ fmap2,
                     const int* __restrict__ kp, const int* __restrict__ idx,
                     unsigned* __restrict__ sb0, unsigned* __restrict__ sb1,
                     unsigned* __restrict__ sb2) {
    __shared__ f32x4 part[256];
    const int n = blockIdx.y;
    if (n >= *kp) return;
    const int t = blockIdx.x;                 // 0..23, pins to XCD t%8
    const int img = idx[n];
    if (t < 13)      dist_min_level<256, 784, 64>(lib0, fmap0, img, t, sb0, part);       // 13 tiles
    else if (t < 20) dist_min_level<512, 196, 32>(lib1, fmap1, img, t - 13, sb1, part);  // 7 tiles
    else             dist_min_level<1024, 49, 16>(lib2, fmap2, img, t - 20, sb2, part);  // 4 tiles
}

// ---------------------------------------------------------------------------
// Kernel 4: FUSED upsample + sum + blur-H + blur-V. 14 band blocks x 16
// output rows. Stage 32 smap rows (reflected) in LDS, H-blur in LDS, V-blur
// reflection-free: hb[r] = Hblur(smap(reflect(y0-8+r))) makes the V tap at
// global row y+j-8 exactly LDS row (y+j-8)-(y0-8).
// ---------------------------------------------------------------------------
static __device__ __forceinline__ void samp(int o, float inv_f, int sz, int& i0, int& i1,
                                            float& fr) {
    float c  = (o + 0.5f) * inv_f - 0.5f;   // inv_f power of two: exact
    float fl = floorf(c);
    fr = c - fl;
    int i = (int)fl;
    i0 = iclamp(i, 0, sz - 1);
    i1 = iclamp(i + 1, 0, sz - 1);
}

static __device__ __forceinline__ float ldsq(const unsigned* __restrict__ sb, int w, int y, int x) {
    return sqrtf(__uint_as_float(sb[y * w + x]));
}

static __device__ __forceinline__ float bilerp_sq(const unsigned* __restrict__ sb, int w,
                                                  int y0, int y1, int x0, int x1,
                                                  float fy, float fx) {
    float a = ldsq(sb, w, y0, x0), b = ldsq(sb, w, y0, x1);
    float c = ldsq(sb, w, y1, x0), d = ldsq(sb, w, y1, x1);
    float top = a + (b - a) * fx;
    float bot = c + (d - c) * fx;
    return top + (bot - top) * fy;
}

static __device__ __forceinline__ int reflect224(int i) {
    if (i < 0) i = -i;
    if (i > 223) i = 446 - i;
    return i;
}

static __device__ __forceinline__ void gauss_w(float* w) {
    float tot = 0.f;
#pragma unroll
    for (int j = 0; j < 17; ++j) {
        float t = (j - 8) * 0.25f;
        w[j] = expf(-0.5f * t * t);
        tot += w[j];
    }
    float inv = 1.f / tot;
#pragma unroll
    for (int j = 0; j < 17; ++j) w[j] *= inv;
}

__global__ __launch_bounds__(256)
void up_blur_kernel(const unsigned* __restrict__ sb0, const unsigned* __restrict__ sb1,
                    const unsigned* __restrict__ sb2, float* __restrict__ outmap) {
    __shared__ float sm[32][224];   // smap at reflected rows y0-8+r
    __shared__ float hb[32][224];   // H-blurred
    const int y0 = blockIdx.x * 16;
    const int tid = threadIdx.x;
    float w[17];
    gauss_w(w);

    // phase 1: upsample+sum at (reflect(y0-8+r), x)
    for (int i = tid; i < 32 * 224; i += 256) {
        const int r = i / 224, x = i - r * 224;
        const int gy = reflect224(y0 - 8 + r);
        int yy0, yy1, xx0, xx1; float fy, fx;
        float v = 0.f;
        samp(gy, 0.25f, 56, yy0, yy1, fy);   samp(x, 0.25f, 56, xx0, xx1, fx);
        v += bilerp_sq(sb0, 56, yy0, yy1, xx0, xx1, fy, fx);
        samp(gy, 0.125f, 28, yy0, yy1, fy);  samp(x, 0.125f, 28, xx0, xx1, fx);
        v += bilerp_sq(sb1, 28, yy0, yy1, xx0, xx1, fy, fx);
        samp(gy, 0.0625f, 14, yy0, yy1, fy); samp(x, 0.0625f, 14, xx0, xx1, fx);
        v += bilerp_sq(sb2, 14, yy0, yy1, xx0, xx1, fy, fx);
        sm[r][x] = v;
    }
    __syncthreads();

    // phase 2: H-blur each staged row (col reflection inside the row)
    for (int i = tid; i < 32 * 224; i += 256) {
        const int r = i / 224, x = i - r * 224;
        float acc = 0.f;
#pragma unroll
        for (int j = 0; j < 17; ++j) acc += w[j] * sm[r][reflect224(x + j - 8)];
        hb[r][x] = acc;
    }
    __syncthreads();

    // phase 3: V-blur -> 16 output rows (LDS row index is reflection-free)
    for (int i = tid; i < 16 * 224; i += 256) {
        const int ry = i / 224, x = i - ry * 224;
        const int y = y0 + ry;
        float acc = 0.f;
#pragma unroll
        for (int j = 0; j < 17; ++j) acc += w[j] * hb[y + j - 8 - (y0 - 8)][x];
        outmap[y * 224 + x] = acc;
    }
}

// ---------------------------------------------------------------------------
// Launch
// ---------------------------------------------------------------------------
extern "C" void kernel_launch(void* const* d_in, const int* in_sizes, int n_in,
                              void* d_out, int out_size, void* d_ws, size_t ws_size,
                              hipStream_t stream) {
    const float* z     = (const float*)d_in[0];
    const float* z_lib = (const float*)d_in[1];
    const float* fmap0 = (const float*)d_in[2];
    const float* fmap1 = (const float*)d_in[3];
    const float* fmap2 = (const float*)d_in[4];
    const float* lib0  = (const float*)d_in[5];
    const float* lib1  = (const float*)d_in[6];
    const float* lib2  = (const float*)d_in[7];
    const int*   kp    = (const int*)d_in[8];
    float* out = (float*)d_out;

    // workspace layout (16B aligned)
    constexpr size_t OFF_IDX   = 0;        // 128 i32
    constexpr size_t OFF_DIST2 = 1024;     // 128 f32
    constexpr size_t OFF_SB0   = 2048;     // 3136 u32
    constexpr size_t OFF_SB1   = 16384;    // 784 u32
    constexpr size_t OFF_SB2   = 20480;    // 196 u32

    char* ws = (char*)d_ws;
    int*      idx   = (int*)(ws + OFF_IDX);
    float*    dist2 = (float*)(ws + OFF_DIST2);
    unsigned* sb0   = (unsigned*)(ws + OFF_SB0);
    unsigned* sb1   = (unsigned*)(ws + OFF_SB1);
    unsigned* sb2   = (unsigned*)(ws + OFF_SB2);

    // 1) row distances + smin init
    row_dist_kernel<<<dim3(NLIB), dim3(256), 0, stream>>>(z, z_lib, dist2, sb0, sb1, sb2);
    // 2) rank-select + z_score
    select_kernel<<<dim3(1), dim3(128), 0, stream>>>(dist2, kp, out, idx);
    // 3) fused per-level distances + min, 24 byte-uniform tiles, 1 n/block
    dist_min_kernel<<<dim3(24, NLIB), dim3(256), 0, stream>>>(
        lib0, fmap0, lib1, fmap1, lib2, fmap2, kp, idx, sb0, sb1, sb2);
    // 4) fused upsample + sum + blur-H + blur-V
    up_blur_kernel<<<dim3(14), dim3(256), 0, stream>>>(sb0, sb1, sb2, out + 1);
}

// Round 8
// 83.748 us; speedup vs baseline: 1.3367x; 1.2961x over previous
//
#include <hip/hip_runtime.h>
#include <math.h>

#define NLIB 128
#define INFBITS 0x7F800000u

typedef float f32x4 __attribute__((ext_vector_type(4)));

static __device__ __forceinline__ int iclamp(int v, int lo, int hi) {
    return v < lo ? lo : (v > hi ? hi : v);
}

// ---------------------------------------------------------------------------
// Kernel 1: FUSED row-distance + rank-select (last-block pattern).
// 128 blocks x 256 thr. Each block: init slice of smin-bits, compute
// dist2[n] = ||z_lib[n]-z||^2. Last block to finish (atomic counter, reset
// by memset each launch) re-reads all dist2 (fenced) and does the
// deterministic fixed-order rank-select + z_score.
// ---------------------------------------------------------------------------
__global__ __launch_bounds__(256)
void knn_fused_kernel(const float* __restrict__ z, const float* __restrict__ z_lib,
                      const int* __restrict__ kp, float* __restrict__ zscore,
                      int* __restrict__ idx, float* __restrict__ dist2,
                      unsigned* __restrict__ done, unsigned* __restrict__ sb0,
                      unsigned* __restrict__ sb1, unsigned* __restrict__ sb2) {
    const int n = blockIdx.x;
    const int tid = threadIdx.x, wave = tid >> 6, lane = tid & 63;
    // distributed init: 128*256 = 32768 >= 4116 words
    const int gid = n * 256 + tid;
    if (gid < 3136)      sb0[gid] = INFBITS;
    else if (gid < 3920) sb1[gid - 3136] = INFBITS;
    else if (gid < 4116) sb2[gid - 3920] = INFBITS;

    const f32x4 a = ((const f32x4*)(z_lib + (size_t)n * 1024))[tid];
    const f32x4 b = ((const f32x4*)z)[tid];
    f32x4 dv = a - b;
    f32x4 sv = dv * dv;
    float acc = sv[0] + sv[1] + sv[2] + sv[3];
    for (int off = 32; off > 0; off >>= 1) acc += __shfl_down(acc, off, 64);
    __shared__ float ws4[4];
    __shared__ int winner;
    if (lane == 0) ws4[wave] = acc;
    __syncthreads();
    if (tid == 0) {
        dist2[n] = ws4[0] + ws4[1] + ws4[2] + ws4[3];
        __threadfence();                       // release dist2 before count
        unsigned old = atomicAdd(done, 1u);
        winner = (old == NLIB - 1) ? 1 : 0;
    }
    __syncthreads();
    if (!winner) return;

    // ---- winner block: select (identical arithmetic to old select_kernel)
    __threadfence();                           // acquire all dist2 stores
    __shared__ float d[NLIB];
    __shared__ float contrib[NLIB];
    if (tid < NLIB) d[tid] = dist2[tid];
    __syncthreads();
    const int k = *kp;
    if (tid < NLIB) {
        const float dd = d[tid];
        int rank = 0;
#pragma unroll 8
        for (int m = 0; m < NLIB; ++m) {
            const float dm = d[m];
            rank += (dm < dd || (dm == dd && m < tid)) ? 1 : 0;
        }
        if (rank < k) idx[rank] = tid;
        contrib[tid] = (rank < k) ? sqrtf(dd) : 0.f;
    }
    __syncthreads();
    if (tid == 0) {
        float s = 0.f;
        for (int m = 0; m < NLIB; ++m) s += contrib[m];   // fixed order
        zscore[0] = s / (float)k;
    }
}

// ---------------------------------------------------------------------------
// Kernel 2: FUSED dist+min, XCD-byte-balanced (proven 82.4µs structure:
// 1 n/block, plain loads — NT/multi-stream regressed, do not reintroduce).
// 24 byte-uniform tiles (262KB lib each): QT = 64/32/16 quads for
// C = 256/512/1024. gridDim.x=24 -> tile t pins to XCD t%8 (fmap slice
// L2-resident, equal bytes/XCD). LDS-combine fixed order; atomicMin(uint
// bits) into smin. No intermediate buffer.
// ---------------------------------------------------------------------------
template <int C, int NQ, int QT>
static __device__ __forceinline__ void dist_min_level(const float* __restrict__ lib,
                                                      const float* __restrict__ fmap,
                                                      int img, int qt,
                                                      unsigned* __restrict__ sb,
                                                      f32x4* __restrict__ part) {
    constexpr int G  = 256 / QT;       // channel groups per block
    constexpr int CW = C / G;          // channels per thread (= 64)
    const int tid = threadIdx.x;
    const int ql  = tid & (QT - 1);
    const int g   = tid / QT;
    const int q   = qt * QT + ql;
    const int qc  = q < NQ ? q : NQ - 1;     // clamp: dup same-address loads
    const f32x4* __restrict__ lp = (const f32x4*)lib + ((size_t)img * C + g * CW) * NQ + qc;
    const f32x4* __restrict__ fp = (const f32x4*)fmap + ((size_t)g * CW) * NQ + qc;
    f32x4 acc = {};
#pragma unroll 8
    for (int c = 0; c < CW; ++c) {
        f32x4 a = lp[(size_t)c * NQ];
        f32x4 f = fp[(size_t)c * NQ];
        f32x4 d = a - f;
        acc += d * d;
    }
    part[tid] = acc;
    __syncthreads();
    if (tid < QT && q < NQ) {
        f32x4 s = part[tid];
#pragma unroll
        for (int gg = 1; gg < G; ++gg) s += part[gg * QT + tid];  // fixed order
        atomicMin(sb + q * 4 + 0, __float_as_uint(s[0]));
        atomicMin(sb + q * 4 + 1, __float_as_uint(s[1]));
        atomicMin(sb + q * 4 + 2, __float_as_uint(s[2]));
        atomicMin(sb + q * 4 + 3, __float_as_uint(s[3]));
    }
}

__global__ __launch_bounds__(256)
void dist_min_kernel(const float* __restrict__ lib0, const float* __restrict__ fmap0,
                     const float* __restrict__ lib1, const float* __restrict__ fmap1,
                     const float* __restrict__ lib2, const float* __restrict__ fmap2,
                     const int* __restrict__ kp, const int* __restrict__ idx,
                     unsigned* __restrict__ sb0, unsigned* __restrict__ sb1,
                     unsigned* __restrict__ sb2) {
    __shared__ f32x4 part[256];
    const int n = blockIdx.y;
    if (n >= *kp) return;
    const int t = blockIdx.x;                 // 0..23, pins to XCD t%8
    const int img = idx[n];
    if (t < 13)      dist_min_level<256, 784, 64>(lib0, fmap0, img, t, sb0, part);       // 13 tiles
    else if (t < 20) dist_min_level<512, 196, 32>(lib1, fmap1, img, t - 13, sb1, part);  // 7 tiles
    else             dist_min_level<1024, 49, 16>(lib2, fmap2, img, t - 20, sb2, part);  // 4 tiles
}

// ---------------------------------------------------------------------------
// Kernel 3: bilinear upsample (half-pixel, edge clamp) of sqrt(smin-bits),
// summed across levels, fused with horizontal 17-tap blur (reflect).
// One block per output row (proven tail — 14-block mega-fusion was latency-
// bound and cost +26µs; keep parallelism high).
// ---------------------------------------------------------------------------
static __device__ __forceinline__ void samp(int o, float inv_f, int sz, int& i0, int& i1,
                                            float& fr) {
    float c  = (o + 0.5f) * inv_f - 0.5f;   // inv_f power of two: exact
    float fl = floorf(c);
    fr = c - fl;
    int i = (int)fl;
    i0 = iclamp(i, 0, sz - 1);
    i1 = iclamp(i + 1, 0, sz - 1);
}

static __device__ __forceinline__ float ldsq(const unsigned* __restrict__ sb, int w, int y, int x) {
    return sqrtf(__uint_as_float(sb[y * w + x]));
}

static __device__ __forceinline__ float bilerp_sq(const unsigned* __restrict__ sb, int w,
                                                  int y0, int y1, int x0, int x1,
                                                  float fy, float fx) {
    float a = ldsq(sb, w, y0, x0), b = ldsq(sb, w, y0, x1);
    float c = ldsq(sb, w, y1, x0), d = ldsq(sb, w, y1, x1);
    float top = a + (b - a) * fx;
    float bot = c + (d - c) * fx;
    return top + (bot - top) * fy;
}

static __device__ __forceinline__ int reflect224(int i) {
    if (i < 0) i = -i;
    if (i > 223) i = 446 - i;
    return i;
}

static __device__ __forceinline__ void gauss_w(float* w) {
    float tot = 0.f;
#pragma unroll
    for (int j = 0; j < 17; ++j) {
        float t = (j - 8) * 0.25f;
        w[j] = expf(-0.5f * t * t);
        tot += w[j];
    }
    float inv = 1.f / tot;
#pragma unroll
    for (int j = 0; j < 17; ++j) w[j] *= inv;
}

__global__ __launch_bounds__(256)
void up_blurh_kernel(const unsigned* __restrict__ sb0, const unsigned* __restrict__ sb1,
                     const unsigned* __restrict__ sb2, float* __restrict__ tmp) {
    __shared__ float row[224];
    const int y = blockIdx.x, x = threadIdx.x;
    int y0, y1, x0, x1; float fy, fx;
    if (x < 224) {
        float v = 0.f;
        samp(y, 0.25f, 56, y0, y1, fy);   samp(x, 0.25f, 56, x0, x1, fx);
        v += bilerp_sq(sb0, 56, y0, y1, x0, x1, fy, fx);
        samp(y, 0.125f, 28, y0, y1, fy);  samp(x, 0.125f, 28, x0, x1, fx);
        v += bilerp_sq(sb1, 28, y0, y1, x0, x1, fy, fx);
        samp(y, 0.0625f, 14, y0, y1, fy); samp(x, 0.0625f, 14, x0, x1, fx);
        v += bilerp_sq(sb2, 14, y0, y1, x0, x1, fy, fx);
        row[x] = v;
    }
    __syncthreads();
    if (x < 224) {
        float w[17];
        gauss_w(w);
        float acc = 0.f;
#pragma unroll
        for (int j = 0; j < 17; ++j) acc += w[j] * row[reflect224(x + j - 8)];
        tmp[y * 224 + x] = acc;
    }
}

__global__ __launch_bounds__(256)
void blur_v_kernel(const float* __restrict__ in, float* __restrict__ out) {
    const int i = blockIdx.x * blockDim.x + threadIdx.x;
    if (i >= 224 * 224) return;
    const int y = i / 224, x = i % 224;
    float w[17];
    gauss_w(w);
    float acc = 0.f;
#pragma unroll
    for (int j = 0; j < 17; ++j) acc += w[j] * in[reflect224(y + j - 8) * 224 + x];
    out[i] = acc;
}

// ---------------------------------------------------------------------------
// Launch
// ---------------------------------------------------------------------------
extern "C" void kernel_launch(void* const* d_in, const int* in_sizes, int n_in,
                              void* d_out, int out_size, void* d_ws, size_t ws_size,
                              hipStream_t stream) {
    const float* z     = (const float*)d_in[0];
    const float* z_lib = (const float*)d_in[1];
    const float* fmap0 = (const float*)d_in[2];
    const float* fmap1 = (const float*)d_in[3];
    const float* fmap2 = (const float*)d_in[4];
    const float* lib0  = (const float*)d_in[5];
    const float* lib1  = (const float*)d_in[6];
    const float* lib2  = (const float*)d_in[7];
    const int*   kp    = (const int*)d_in[8];
    float* out = (float*)d_out;

    // workspace layout (16B aligned)
    constexpr size_t OFF_IDX   = 0;        // 128 i32
    constexpr size_t OFF_DIST2 = 1024;     // 128 f32
    constexpr size_t OFF_SB0   = 2048;     // 3136 u32
    constexpr size_t OFF_SB1   = 16384;    // 784 u32
    constexpr size_t OFF_SB2   = 20480;    // 196 u32
    constexpr size_t OFF_DONE  = 22528;    // 1 u32 (memset each launch)
    constexpr size_t OFF_TMP   = 24576;    // 50176 f32

    char* ws = (char*)d_ws;
    int*      idx   = (int*)(ws + OFF_IDX);
    float*    dist2 = (float*)(ws + OFF_DIST2);
    unsigned* sb0   = (unsigned*)(ws + OFF_SB0);
    unsigned* sb1   = (unsigned*)(ws + OFF_SB1);
    unsigned* sb2   = (unsigned*)(ws + OFF_SB2);
    unsigned* done  = (unsigned*)(ws + OFF_DONE);
    float*    tmp   = (float*)(ws + OFF_TMP);

    // 0) reset completion counter (graph-capturable async memset)
    hipMemsetAsync(done, 0, sizeof(unsigned), stream);
    // 1) row distances + smin init + last-block rank-select + z_score
    knn_fused_kernel<<<dim3(NLIB), dim3(256), 0, stream>>>(
        z, z_lib, kp, out, idx, dist2, done, sb0, sb1, sb2);
    // 2) fused per-level distances + min, 24 byte-uniform tiles, 1 n/block
    dist_min_kernel<<<dim3(24, NLIB), dim3(256), 0, stream>>>(
        lib0, fmap0, lib1, fmap1, lib2, fmap2, kp, idx, sb0, sb1, sb2);
    // 3) upsample + sum + blur-H
    up_blurh_kernel<<<dim3(224), dim3(256), 0, stream>>>(sb0, sb1, sb2, tmp);
    // 4) blur-V
    blur_v_kernel<<<dim3(196), dim3(256), 0, stream>>>(tmp, out + 1);
}